// Round 2
// baseline (193.583 us; speedup 1.0000x reference)
//
#include <hip/hip_runtime.h>
#include <hip/hip_bf16.h>

#define B_  2
#define S_  2048
#define D_  1024
#define H_  16
#define DK_ 64
#define M_  (B_ * S_)   // 4096

typedef short short8 __attribute__((ext_vector_type(8)));
typedef float float4v __attribute__((ext_vector_type(4)));

static __device__ __forceinline__ float bf16bits_to_f32(ushort u) {
    union { unsigned int i; float f; } cv;
    cv.i = ((unsigned int)u) << 16;
    return cv.f;
}
static __device__ __forceinline__ ushort f32_to_bf16bits(float f) {
    union { __hip_bfloat16 h; ushort u; } cv;
    cv.h = __float2bfloat16(f);
    return cv.u;
}

// ---------------------------------------------------------------------------
// Kernel -1: convert fp32 -> bf16 (for Q / X). n must be divisible by 8*256.
// ---------------------------------------------------------------------------
__global__ __launch_bounds__(256) void convert_bf16(
    const float* __restrict__ in, ushort* __restrict__ out)
{
    const int i = (blockIdx.x * 256 + threadIdx.x) * 8;
    float4v a = *(const float4v*)(in + i);
    float4v b = *(const float4v*)(in + i + 4);
    short8 o;
    o[0] = (short)f32_to_bf16bits(a[0]); o[1] = (short)f32_to_bf16bits(a[1]);
    o[2] = (short)f32_to_bf16bits(a[2]); o[3] = (short)f32_to_bf16bits(a[3]);
    o[4] = (short)f32_to_bf16bits(b[0]); o[5] = (short)f32_to_bf16bits(b[1]);
    o[6] = (short)f32_to_bf16bits(b[2]); o[7] = (short)f32_to_bf16bits(b[3]);
    *(short8*)(out + i) = o;
}

// ---------------------------------------------------------------------------
// Kernel 0: transpose + convert the three fp32 weight matrices
// W[k][n] (fp32) -> Wt[n][k] (bf16), so the GEMM B-operand fragments read
// contiguous-in-K from LDS.
// ---------------------------------------------------------------------------
__global__ __launch_bounds__(256) void transpose_w(
    const float* __restrict__ W0, const float* __restrict__ W1,
    const float* __restrict__ W2, ushort* __restrict__ Wt)
{
    const float* W = (blockIdx.z == 0) ? W0 : ((blockIdx.z == 1) ? W1 : W2);
    ushort* out = Wt + (size_t)blockIdx.z * D_ * D_;

    __shared__ ushort tile[64 * 72];   // [k_local][n_local] bf16, stride 72

    int n0 = blockIdx.x * 64, k0 = blockIdx.y * 64;
    int t = threadIdx.x;
    int r = t >> 3, g = t & 7;

    #pragma unroll
    for (int p = 0; p < 2; ++p) {
        int rr = r + p * 32;  // k_local
        const float* src = W + (size_t)(k0 + rr) * D_ + n0 + g * 8;
        float4v a = *(const float4v*)src;
        float4v b = *(const float4v*)(src + 4);
        short8 o;
        o[0] = (short)f32_to_bf16bits(a[0]); o[1] = (short)f32_to_bf16bits(a[1]);
        o[2] = (short)f32_to_bf16bits(a[2]); o[3] = (short)f32_to_bf16bits(a[3]);
        o[4] = (short)f32_to_bf16bits(b[0]); o[5] = (short)f32_to_bf16bits(b[1]);
        o[6] = (short)f32_to_bf16bits(b[2]); o[7] = (short)f32_to_bf16bits(b[3]);
        *(short8*)&tile[rr * 72 + g * 8] = o;
    }
    __syncthreads();
    #pragma unroll
    for (int p = 0; p < 2; ++p) {
        int rr = r + p * 32;  // n_local (output row)
        short8 v;
        #pragma unroll
        for (int i = 0; i < 8; ++i)
            v[i] = (short)tile[(g * 8 + i) * 72 + rr];
        *(short8*)(out + (size_t)(n0 + rr) * D_ + k0 + g * 8) = v;
    }
}

// ---------------------------------------------------------------------------
// Kernel 1: fused QKV projection.  y = X @ W + b, X:[4096,1024] bf16 (pre-
// converted), Wt:[1024,1024] bf16 n-major.  blockIdx.z in {0,1,2} = q/k/v.
// Output layouts (bf16 workspace):
//   q,k : [B][H][S][DK]
//   v   : [B][H][DK][S]   (transposed so attention PV B-operand is
//                          contiguous-in-K when staged)
// 128x128 tile, BK=32, 4 waves as 2x2, each wave 64x64 = 4x4 MFMA 16x16x32.
// ---------------------------------------------------------------------------
__global__ __launch_bounds__(256) void proj_gemm(
    const ushort* __restrict__ X,    // [4096][1024] bf16
    const ushort* __restrict__ Wt,   // [3][1024][1024] bf16, n-major
    const float* __restrict__ b0, const float* __restrict__ b1,
    const float* __restrict__ b2,
    ushort* __restrict__ qkv)        // [3][4M] bf16
{
    const int z = blockIdx.z;
    const ushort* Wtz  = Wt + (size_t)z * D_ * D_;
    const float* bias = (z == 0) ? b0 : ((z == 1) ? b1 : b2);
    ushort* out = qkv + (size_t)z * M_ * D_;

    const int m0 = blockIdx.x * 128, n0 = blockIdx.y * 128;

    __shared__ ushort As[128 * 40];   // [m_local][k_local], stride 40 (pad)
    __shared__ ushort Bst[128 * 40];  // [n_local][k_local], stride 40 (pad)

    const int t = threadIdx.x;
    const int lane = t & 63, wid = t >> 6;
    const int quad = lane >> 4, l16 = lane & 15;
    const int wr = wid >> 1, wc = wid & 1;

    const int r = t >> 2, g = t & 3;   // staging: 64 rows x 4 groups of 8

    float4v acc[4][4] = {};

    for (int k0 = 0; k0 < D_; k0 += 32) {
        __syncthreads();
        *(short8*)&As[r * 40 + g * 8] =
            *(const short8*)(X + (size_t)(m0 + r) * D_ + k0 + g * 8);
        *(short8*)&As[(r + 64) * 40 + g * 8] =
            *(const short8*)(X + (size_t)(m0 + r + 64) * D_ + k0 + g * 8);
        *(short8*)&Bst[r * 40 + g * 8] =
            *(const short8*)(Wtz + (size_t)(n0 + r) * D_ + k0 + g * 8);
        *(short8*)&Bst[(r + 64) * 40 + g * 8] =
            *(const short8*)(Wtz + (size_t)(n0 + r + 64) * D_ + k0 + g * 8);
        __syncthreads();

        short8 a[4], bb[4];
        #pragma unroll
        for (int i = 0; i < 4; ++i)
            a[i] = *(short8*)&As[(wr * 64 + i * 16 + l16) * 40 + quad * 8];
        #pragma unroll
        for (int j = 0; j < 4; ++j)
            bb[j] = *(short8*)&Bst[(wc * 64 + j * 16 + l16) * 40 + quad * 8];
        #pragma unroll
        for (int i = 0; i < 4; ++i)
            #pragma unroll
            for (int j = 0; j < 4; ++j)
                acc[i][j] = __builtin_amdgcn_mfma_f32_16x16x32_bf16(
                    a[i], bb[j], acc[i][j], 0, 0, 0);
    }

    // epilogue: +bias (fp32), cast bf16, scatter into head layout
    #pragma unroll
    for (int j = 0; j < 4; ++j) {
        const int col = n0 + wc * 64 + j * 16 + l16;
        const float bv = bias[col];
        const int h = col >> 6, dk = col & (DK_ - 1);
        #pragma unroll
        for (int i = 0; i < 4; ++i) {
            #pragma unroll
            for (int rr = 0; rr < 4; ++rr) {
                const int row = m0 + wr * 64 + i * 16 + quad * 4 + rr;
                const int bidx = row >> 11;       // / S_
                const int s = row & (S_ - 1);
                const float v = acc[i][j][rr] + bv;
                size_t addr;
                if (z == 2)
                    addr = ((size_t)(bidx * H_ + h) * DK_ + dk) * S_ + s;
                else
                    addr = ((size_t)(bidx * H_ + h) * S_ + s) * DK_ + dk;
                out[addr] = f32_to_bf16bits(v);
            }
        }
    }
}

// ---------------------------------------------------------------------------
// Kernel 2: attention.  One block = (b, h, 64 q-rows).  Raw exp (no max
// subtraction per the reference) means no online rescale: accumulate row-sum
// of exp and un-normalized P@V across k-tiles, normalize once at the end.
// k-tiles fully beyond length[b] are skipped (lengths uniform 1..S: ~2x save).
// ---------------------------------------------------------------------------
__global__ __launch_bounds__(256) void attention(
    const ushort* __restrict__ qkv, const int* __restrict__ length,
    float* __restrict__ out)
{
    const int b = blockIdx.z, h = blockIdx.y, q0 = blockIdx.x * 64;
    int len = length[b];
    if (len > S_) len = S_;
    if (len < 1) len = 1;
    const int nkt = (len + 63) >> 6;

    const ushort* qb = qkv + ((size_t)(b * H_ + h) * S_ + q0) * DK_;
    const ushort* kb = qkv + (size_t)M_ * D_ + (size_t)(b * H_ + h) * S_ * DK_;
    const ushort* vb = qkv + (size_t)2 * M_ * D_ + (size_t)(b * H_ + h) * DK_ * S_;

    __shared__ ushort Qs[64 * 72];   // [q_local][dk]
    __shared__ ushort Ks[64 * 72];   // [key_local][dk]
    __shared__ ushort Vst[64 * 72];  // [dk][key_local]  (v pre-transposed)
    __shared__ ushort Ps[64 * 72];   // [q_local][key_local] bf16 exp-scores

    const int t = threadIdx.x, lane = t & 63, wid = t >> 6;
    const int quad = lane >> 4, l16 = lane & 15;
    const int r = t >> 3, g = t & 7;   // staging: 32 rows x 8 groups, x2

    // Q tile (once)
    *(short8*)&Qs[r * 72 + g * 8] =
        *(const short8*)(qb + (size_t)r * DK_ + g * 8);
    *(short8*)&Qs[(r + 32) * 72 + g * 8] =
        *(const short8*)(qb + (size_t)(r + 32) * DK_ + g * 8);

    float4v cacc[4] = {};
    float rs[4] = {0.f, 0.f, 0.f, 0.f};

    for (int kt = 0; kt < nkt; ++kt) {
        __syncthreads();   // also covers initial Qs visibility
        *(short8*)&Ks[r * 72 + g * 8] =
            *(const short8*)(kb + (size_t)(kt * 64 + r) * DK_ + g * 8);
        *(short8*)&Ks[(r + 32) * 72 + g * 8] =
            *(const short8*)(kb + (size_t)(kt * 64 + r + 32) * DK_ + g * 8);
        *(short8*)&Vst[r * 72 + g * 8] =
            *(const short8*)(vb + (size_t)r * S_ + kt * 64 + g * 8);
        *(short8*)&Vst[(r + 32) * 72 + g * 8] =
            *(const short8*)(vb + (size_t)(r + 32) * S_ + kt * 64 + g * 8);
        __syncthreads();

        // S-tile = Q K^T for this wave's private 16-row strip
        float4v sacc[4] = {};
        #pragma unroll
        for (int ks = 0; ks < 2; ++ks) {
            short8 a = *(short8*)&Qs[(wid * 16 + l16) * 72 + ks * 32 + quad * 8];
            #pragma unroll
            for (int ct = 0; ct < 4; ++ct) {
                short8 bb = *(short8*)&Ks[(ct * 16 + l16) * 72 + ks * 32 + quad * 8];
                sacc[ct] = __builtin_amdgcn_mfma_f32_16x16x32_bf16(
                    a, bb, sacc[ct], 0, 0, 0);
            }
        }

        // exp + key mask + rowsum; write P strip (C-layout -> LDS)
        #pragma unroll
        for (int ct = 0; ct < 4; ++ct) {
            const int key = kt * 64 + ct * 16 + l16;
            #pragma unroll
            for (int rr = 0; rr < 4; ++rr) {
                float val = 0.f;
                if (key < len) val = __expf(sacc[ct][rr] * 0.125f);
                rs[rr] += val;
                Ps[(wid * 16 + quad * 4 + rr) * 72 + ct * 16 + l16] =
                    f32_to_bf16bits(val);
            }
        }

        // P @ V (strip is wave-private: same-wave LDS RAW, compiler inserts
        // the lgkmcnt wait; no cross-wave barrier needed)
        #pragma unroll
        for (int ks = 0; ks < 2; ++ks) {
            short8 ap = *(short8*)&Ps[(wid * 16 + l16) * 72 + ks * 32 + quad * 8];
            #pragma unroll
            for (int ct = 0; ct < 4; ++ct) {
                short8 bv8 = *(short8*)&Vst[(ct * 16 + l16) * 72 + ks * 32 + quad * 8];
                cacc[ct] = __builtin_amdgcn_mfma_f32_16x16x32_bf16(
                    ap, bv8, cacc[ct], 0, 0, 0);
            }
        }
    }

    // reduce row-sums across the 16 lanes of each quad-row group
    #pragma unroll
    for (int rr = 0; rr < 4; ++rr) {
        float v = rs[rr];
        #pragma unroll
        for (int off = 1; off < 16; off <<= 1)
            v += __shfl_xor(v, off, 16);
        rs[rr] = v;
    }

    // normalize + store fp32
    #pragma unroll
    for (int ct = 0; ct < 4; ++ct) {
        #pragma unroll
        for (int rr = 0; rr < 4; ++rr) {
            const int q = q0 + wid * 16 + quad * 4 + rr;
            const int d = h * 64 + ct * 16 + l16;
            out[((size_t)b * S_ + q) * D_ + d] = cacc[ct][rr] / (rs[rr] + 1e-8f);
        }
    }
}

// ---------------------------------------------------------------------------
extern "C" void kernel_launch(void* const* d_in, const int* in_sizes, int n_in,
                              void* d_out, int out_size, void* d_ws, size_t ws_size,
                              hipStream_t stream)
{
    const float* Q   = (const float*)d_in[0];
    const int*   len = (const int*)d_in[1];
    const float* Wq  = (const float*)d_in[2];
    const float* bq  = (const float*)d_in[3];
    const float* Wk  = (const float*)d_in[4];
    const float* bk  = (const float*)d_in[5];
    const float* Wv  = (const float*)d_in[6];
    const float* bv  = (const float*)d_in[7];
    float* out = (float*)d_out;

    ushort* ws  = (ushort*)d_ws;
    ushort* Xb  = ws;                                   // 4M bf16 = 8 MB
    ushort* Wt  = ws + (size_t)M_ * D_;                 // 3M bf16 = 6 MB
    ushort* qkv = Wt + (size_t)3 * D_ * D_;             // 12M bf16 = 24 MB

    convert_bf16<<<dim3(M_ * D_ / (8 * 256)), 256, 0, stream>>>(Q, Xb);

    dim3 gT(16, 16, 3);
    transpose_w<<<gT, 256, 0, stream>>>(Wq, Wk, Wv, Wt);

    dim3 gP(M_ / 128, D_ / 128, 3);
    proj_gemm<<<gP, 256, 0, stream>>>(Xb, Wt, bq, bk, bv, qkv);

    dim3 gA(S_ / 64, H_, B_);
    attention<<<gA, 256, 0, stream>>>(qkv, len, out);
}

// Round 3
// 192.835 us; speedup vs baseline: 1.0039x; 1.0039x over previous
//
#include <hip/hip_runtime.h>
#include <hip/hip_bf16.h>

#define B_  2
#define S_  2048
#define D_  1024
#define H_  16
#define DK_ 64
#define M_  (B_ * S_)   // 4096

typedef short short8 __attribute__((ext_vector_type(8)));
typedef float float4v __attribute__((ext_vector_type(4)));

static __device__ __forceinline__ ushort f32_to_bf16bits(float f) {
    union { __hip_bfloat16 h; ushort u; } cv;
    cv.h = __float2bfloat16(f);
    return cv.u;
}

// async global->LDS, 16B per lane.  HW semantics: lands at wave-uniform base
// + lane*16; we pass the per-lane pointer (== base + lane*16) for clarity.
static __device__ __forceinline__ void glds16(const ushort* g, ushort* l) {
    __builtin_amdgcn_global_load_lds(
        (const __attribute__((address_space(1))) unsigned int*)g,
        (__attribute__((address_space(3))) unsigned int*)l, 16, 0, 0);
}

// ---------------------------------------------------------------------------
// fp32 -> bf16 convert (for X = Q input)
// ---------------------------------------------------------------------------
__global__ __launch_bounds__(256) void convert_bf16(
    const float* __restrict__ in, ushort* __restrict__ out)
{
    const int i = (blockIdx.x * 256 + threadIdx.x) * 8;
    float4v a = *(const float4v*)(in + i);
    float4v b = *(const float4v*)(in + i + 4);
    short8 o;
    o[0] = (short)f32_to_bf16bits(a[0]); o[1] = (short)f32_to_bf16bits(a[1]);
    o[2] = (short)f32_to_bf16bits(a[2]); o[3] = (short)f32_to_bf16bits(a[3]);
    o[4] = (short)f32_to_bf16bits(b[0]); o[5] = (short)f32_to_bf16bits(b[1]);
    o[6] = (short)f32_to_bf16bits(b[2]); o[7] = (short)f32_to_bf16bits(b[3]);
    *(short8*)(out + i) = o;
}

// ---------------------------------------------------------------------------
// transpose + convert W[k][n] fp32 -> Wt[n][k] bf16
// ---------------------------------------------------------------------------
__global__ __launch_bounds__(256) void transpose_w(
    const float* __restrict__ W0, const float* __restrict__ W1,
    const float* __restrict__ W2, ushort* __restrict__ Wt)
{
    const float* W = (blockIdx.z == 0) ? W0 : ((blockIdx.z == 1) ? W1 : W2);
    ushort* out = Wt + (size_t)blockIdx.z * D_ * D_;

    __shared__ ushort tile[64 * 72];

    int n0 = blockIdx.x * 64, k0 = blockIdx.y * 64;
    int t = threadIdx.x;
    int r = t >> 3, g = t & 7;

    #pragma unroll
    for (int p = 0; p < 2; ++p) {
        int rr = r + p * 32;
        const float* src = W + (size_t)(k0 + rr) * D_ + n0 + g * 8;
        float4v a = *(const float4v*)src;
        float4v b = *(const float4v*)(src + 4);
        short8 o;
        o[0] = (short)f32_to_bf16bits(a[0]); o[1] = (short)f32_to_bf16bits(a[1]);
        o[2] = (short)f32_to_bf16bits(a[2]); o[3] = (short)f32_to_bf16bits(a[3]);
        o[4] = (short)f32_to_bf16bits(b[0]); o[5] = (short)f32_to_bf16bits(b[1]);
        o[6] = (short)f32_to_bf16bits(b[2]); o[7] = (short)f32_to_bf16bits(b[3]);
        *(short8*)&tile[rr * 72 + g * 8] = o;
    }
    __syncthreads();
    #pragma unroll
    for (int p = 0; p < 2; ++p) {
        int rr = r + p * 32;
        short8 v;
        #pragma unroll
        for (int i = 0; i < 8; ++i)
            v[i] = (short)tile[(g * 8 + i) * 72 + rr];
        *(short8*)(out + (size_t)(n0 + rr) * D_ + k0 + g * 8) = v;
    }
}

// ---------------------------------------------------------------------------
// fused QKV projection, m97-style: 128x128 tile, BK=64, global_load_lds
// width=16, unpadded XOR-swizzled LDS (rows = 128B, 16B chunk c stored at
// c ^ (row&7); fragment reads then alias exactly 2 lanes/bank = free).
// ---------------------------------------------------------------------------
__global__ __launch_bounds__(256) void proj_gemm(
    const ushort* __restrict__ X,    // [4096][1024] bf16
    const ushort* __restrict__ Wt,   // [3][1024][1024] bf16, n-major
    const float* __restrict__ b0, const float* __restrict__ b1,
    const float* __restrict__ b2,
    ushort* __restrict__ qkv)        // [3][4M] bf16
{
    const int z = blockIdx.z;
    const ushort* Wtz  = Wt + (size_t)z * D_ * D_;
    const float* bias = (z == 0) ? b0 : ((z == 1) ? b1 : b2);
    ushort* out = qkv + (size_t)z * M_ * D_;

    const int m0 = blockIdx.x * 128, n0 = blockIdx.y * 128;

    __shared__ ushort As[128 * 64];   // 16 KB, swizzled
    __shared__ ushort Bs[128 * 64];   // 16 KB, swizzled

    const int t = threadIdx.x;
    const int lane = t & 63, wid = t >> 6;
    const int quad = lane >> 4, l16 = lane & 15;
    const int wr = wid >> 1, wc = wid & 1;

    float4v acc[4][4] = {};

    for (int k0 = 0; k0 < D_; k0 += 64) {
        __syncthreads();
        // each wave stages 32 rows of A and 32 rows of B: 4 glds each
        #pragma unroll
        for (int j = 0; j < 4; ++j) {
            const int cid = wid * 256 + j * 64 + lane;   // 16B chunk id
            const int row = cid >> 3;
            const int cl  = (cid & 7) ^ (row & 7);       // logical k-chunk
            glds16(X   + (size_t)(m0 + row) * D_ + k0 + cl * 8, &As[cid * 8]);
            glds16(Wtz + (size_t)(n0 + row) * D_ + k0 + cl * 8, &Bs[cid * 8]);
        }
        __syncthreads();

        #pragma unroll
        for (int ks = 0; ks < 2; ++ks) {
            short8 a[4], bb[4];
            #pragma unroll
            for (int i = 0; i < 4; ++i) {
                const int r = wr * 64 + i * 16 + l16;
                const int ph = (ks * 4 + quad) ^ (r & 7);
                a[i] = *(short8*)&As[r * 64 + ph * 8];
            }
            #pragma unroll
            for (int j = 0; j < 4; ++j) {
                const int r = wc * 64 + j * 16 + l16;
                const int ph = (ks * 4 + quad) ^ (r & 7);
                bb[j] = *(short8*)&Bs[r * 64 + ph * 8];
            }
            #pragma unroll
            for (int i = 0; i < 4; ++i)
                #pragma unroll
                for (int j = 0; j < 4; ++j)
                    acc[i][j] = __builtin_amdgcn_mfma_f32_16x16x32_bf16(
                        a[i], bb[j], acc[i][j], 0, 0, 0);
        }
    }

    // epilogue: +bias (fp32), cast bf16, scatter into head layout
    #pragma unroll
    for (int j = 0; j < 4; ++j) {
        const int col = n0 + wc * 64 + j * 16 + l16;
        const float bv = bias[col];
        const int h = col >> 6, dk = col & (DK_ - 1);
        #pragma unroll
        for (int i = 0; i < 4; ++i) {
            #pragma unroll
            for (int rr = 0; rr < 4; ++rr) {
                const int row = m0 + wr * 64 + i * 16 + quad * 4 + rr;
                const int bidx = row >> 11;
                const int s = row & (S_ - 1);
                const float v = acc[i][j][rr] + bv;
                size_t addr;
                if (z == 2)
                    addr = ((size_t)(bidx * H_ + h) * DK_ + dk) * S_ + s;
                else
                    addr = ((size_t)(bidx * H_ + h) * S_ + s) * DK_ + dk;
                out[addr] = f32_to_bf16bits(v);
            }
        }
    }
}

// ---------------------------------------------------------------------------
// attention: block = (b, h, 128 q-rows), 4 waves x 32 q-rows (2 strips of 16).
// Raw exp (no max-sub) => no online rescale: accumulate exp row-sums and
// un-normalized P@V over 64-wide k-tiles, skip tiles beyond length[b],
// normalize once.  All tiles staged via global_load_lds into swizzled LDS.
// ---------------------------------------------------------------------------
__global__ __launch_bounds__(256) void attention(
    const ushort* __restrict__ qkv, const int* __restrict__ length,
    float* __restrict__ out)
{
    const int b = blockIdx.z, h = blockIdx.y, q0 = blockIdx.x * 128;
    int len = length[b];
    if (len > S_) len = S_;
    if (len < 1) len = 1;
    const int nkt = (len + 63) >> 6;

    const ushort* qb = qkv + ((size_t)(b * H_ + h) * S_ + q0) * DK_;
    const ushort* kb = qkv + (size_t)M_ * D_ + (size_t)(b * H_ + h) * S_ * DK_;
    const ushort* vb = qkv + (size_t)2 * M_ * D_ + (size_t)(b * H_ + h) * DK_ * S_;

    __shared__ ushort Qs[128 * 64];  // [q][dk]   16 KB swizzled
    __shared__ ushort Ks[64 * 64];   // [key][dk]  8 KB swizzled
    __shared__ ushort Vs[64 * 64];   // [dk][key]  8 KB swizzled
    __shared__ ushort Ps[128 * 64];  // [q][key]  16 KB swizzled (wave-private strips)

    const int t = threadIdx.x, lane = t & 63, wid = t >> 6;
    const int quad = lane >> 4, l16 = lane & 15;

    // stage Q once (128 rows x 128B): 4 glds per wave
    #pragma unroll
    for (int j = 0; j < 4; ++j) {
        const int cid = wid * 256 + j * 64 + lane;
        const int row = cid >> 3;
        const int cl  = (cid & 7) ^ (row & 7);
        glds16(qb + (size_t)row * DK_ + cl * 8, &Qs[cid * 8]);
    }

    float4v cacc[2][4] = {};
    float rs[2][4] = {};

    for (int kt = 0; kt < nkt; ++kt) {
        __syncthreads();   // drains vmcnt (covers Q on iter 0, K/V reuse after)
        #pragma unroll
        for (int j = 0; j < 2; ++j) {
            const int cid = wid * 128 + j * 64 + lane;
            const int row = cid >> 3;
            const int cl  = (cid & 7) ^ (row & 7);
            glds16(kb + (size_t)(kt * 64 + row) * DK_ + cl * 8, &Ks[cid * 8]);
            glds16(vb + (size_t)row * S_ + kt * 64 + cl * 8,    &Vs[cid * 8]);
        }
        __syncthreads();

        #pragma unroll
        for (int st = 0; st < 2; ++st) {
            const int qr = wid * 32 + st * 16 + l16;   // this lane's A-row

            // S-strip = Q K^T  (16 q-rows x 64 keys)
            float4v sacc[4] = {};
            #pragma unroll
            for (int ks = 0; ks < 2; ++ks) {
                const int pha = (ks * 4 + quad) ^ (qr & 7);
                short8 a = *(short8*)&Qs[qr * 64 + pha * 8];
                #pragma unroll
                for (int ct = 0; ct < 4; ++ct) {
                    const int kr = ct * 16 + l16;
                    const int phb = (ks * 4 + quad) ^ (kr & 7);
                    short8 bb = *(short8*)&Ks[kr * 64 + phb * 8];
                    sacc[ct] = __builtin_amdgcn_mfma_f32_16x16x32_bf16(
                        a, bb, sacc[ct], 0, 0, 0);
                }
            }

            // exp + mask + rowsum; write P strip (C-layout -> swizzled LDS)
            #pragma unroll
            for (int ct = 0; ct < 4; ++ct) {
                const int key = kt * 64 + ct * 16 + l16;
                const int c   = ct * 2 + (l16 >> 3);    // logical 16B chunk
                #pragma unroll
                for (int rr = 0; rr < 4; ++rr) {
                    const int prow = wid * 32 + st * 16 + quad * 4 + rr;
                    float val = 0.f;
                    if (key < len) val = __expf(sacc[ct][rr] * 0.125f);
                    rs[st][rr] += val;
                    const int ph = c ^ (prow & 7);
                    Ps[prow * 64 + ph * 8 + (l16 & 7)] = f32_to_bf16bits(val);
                }
            }

            // P @ V  (strip is wave-private: same-wave LDS RAW, no barrier)
            #pragma unroll
            for (int ks = 0; ks < 2; ++ks) {
                const int pha = (ks * 4 + quad) ^ (qr & 7);
                short8 ap = *(short8*)&Ps[qr * 64 + pha * 8];
                #pragma unroll
                for (int ct = 0; ct < 4; ++ct) {
                    const int vr = ct * 16 + l16;       // dk row
                    const int phb = (ks * 4 + quad) ^ (vr & 7);
                    short8 vv = *(short8*)&Vs[vr * 64 + phb * 8];
                    cacc[st][ct] = __builtin_amdgcn_mfma_f32_16x16x32_bf16(
                        ap, vv, cacc[st][ct], 0, 0, 0);
                }
            }
        }
    }

    // reduce row-sums across the 16 lanes of each quad-row group
    #pragma unroll
    for (int st = 0; st < 2; ++st)
        #pragma unroll
        for (int rr = 0; rr < 4; ++rr) {
            float v = rs[st][rr];
            #pragma unroll
            for (int off = 1; off < 16; off <<= 1)
                v += __shfl_xor(v, off, 16);
            rs[st][rr] = v;
        }

    // normalize + store fp32
    #pragma unroll
    for (int st = 0; st < 2; ++st)
        #pragma unroll
        for (int ct = 0; ct < 4; ++ct)
            #pragma unroll
            for (int rr = 0; rr < 4; ++rr) {
                const int q = q0 + wid * 32 + st * 16 + quad * 4 + rr;
                const int d = h * 64 + ct * 16 + l16;
                out[((size_t)b * S_ + q) * D_ + d] =
                    cacc[st][ct][rr] / (rs[st][rr] + 1e-8f);
            }
}

// ---------------------------------------------------------------------------
extern "C" void kernel_launch(void* const* d_in, const int* in_sizes, int n_in,
                              void* d_out, int out_size, void* d_ws, size_t ws_size,
                              hipStream_t stream)
{
    const float* Q   = (const float*)d_in[0];
    const int*   len = (const int*)d_in[1];
    const float* Wq  = (const float*)d_in[2];
    const float* bq  = (const float*)d_in[3];
    const float* Wk  = (const float*)d_in[4];
    const float* bk  = (const float*)d_in[5];
    const float* Wv  = (const float*)d_in[6];
    const float* bv  = (const float*)d_in[7];
    float* out = (float*)d_out;

    ushort* ws  = (ushort*)d_ws;
    ushort* Xb  = ws;                                   // 4M bf16 = 8 MB
    ushort* Wt  = ws + (size_t)M_ * D_;                 // 3M bf16 = 6 MB
    ushort* qkv = Wt + (size_t)3 * D_ * D_;             // 12M bf16 = 24 MB

    convert_bf16<<<dim3(M_ * D_ / (8 * 256)), 256, 0, stream>>>(Q, Xb);

    dim3 gT(16, 16, 3);
    transpose_w<<<gT, 256, 0, stream>>>(Wq, Wk, Wv, Wt);

    dim3 gP(M_ / 128, D_ / 128, 3);
    proj_gemm<<<gP, 256, 0, stream>>>(Xb, Wt, bq, bk, bv, qkv);

    dim3 gA(S_ / 128, H_, B_);
    attention<<<gA, 256, 0, stream>>>(qkv, len, out);
}

// Round 4
// 176.999 us; speedup vs baseline: 1.0937x; 1.0895x over previous
//
#include <hip/hip_runtime.h>
#include <hip/hip_bf16.h>

#define B_  2
#define S_  2048
#define D_  1024
#define H_  16
#define DK_ 64
#define M_  (B_ * S_)   // 4096

typedef short short8 __attribute__((ext_vector_type(8)));
typedef float float4v __attribute__((ext_vector_type(4)));

static __device__ __forceinline__ ushort f32_to_bf16bits(float f) {
    union { __hip_bfloat16 h; ushort u; } cv;
    cv.h = __float2bfloat16(f);
    return cv.u;
}

// async global->LDS, 16B per lane (lands at wave-uniform base + lane*16)
static __device__ __forceinline__ void glds16(const ushort* g, ushort* l) {
    __builtin_amdgcn_global_load_lds(
        (const __attribute__((address_space(1))) unsigned int*)g,
        (__attribute__((address_space(3))) unsigned int*)l, 16, 0, 0);
}

// ---------------------------------------------------------------------------
// prep: z in [0,3) -> transpose+convert W_z[k][n] fp32 -> Wt[n][k] bf16
//       z in [3,11) -> convert X fp32 -> bf16   (one dispatch, fewer gaps)
// ---------------------------------------------------------------------------
__global__ __launch_bounds__(256) void prep(
    const float* __restrict__ X, const float* __restrict__ W0,
    const float* __restrict__ W1, const float* __restrict__ W2,
    ushort* __restrict__ Xb, ushort* __restrict__ Wt)
{
    const int z = blockIdx.z;
    const int t = threadIdx.x;

    if (z >= 3) {   // convert X
        const int blk = (z - 3) * 256 + blockIdx.y * 16 + blockIdx.x;
        const int i = blk * 2048 + t * 8;
        float4v a = *(const float4v*)(X + i);
        float4v b = *(const float4v*)(X + i + 4);
        short8 o;
        o[0] = (short)f32_to_bf16bits(a[0]); o[1] = (short)f32_to_bf16bits(a[1]);
        o[2] = (short)f32_to_bf16bits(a[2]); o[3] = (short)f32_to_bf16bits(a[3]);
        o[4] = (short)f32_to_bf16bits(b[0]); o[5] = (short)f32_to_bf16bits(b[1]);
        o[6] = (short)f32_to_bf16bits(b[2]); o[7] = (short)f32_to_bf16bits(b[3]);
        *(short8*)(Xb + i) = o;
        return;
    }

    const float* W = (z == 0) ? W0 : ((z == 1) ? W1 : W2);
    ushort* out = Wt + (size_t)z * D_ * D_;

    __shared__ ushort tile[64 * 72];
    int n0 = blockIdx.x * 64, k0 = blockIdx.y * 64;
    int r = t >> 3, g = t & 7;

    #pragma unroll
    for (int p = 0; p < 2; ++p) {
        int rr = r + p * 32;
        const float* src = W + (size_t)(k0 + rr) * D_ + n0 + g * 8;
        float4v a = *(const float4v*)src;
        float4v b = *(const float4v*)(src + 4);
        short8 o;
        o[0] = (short)f32_to_bf16bits(a[0]); o[1] = (short)f32_to_bf16bits(a[1]);
        o[2] = (short)f32_to_bf16bits(a[2]); o[3] = (short)f32_to_bf16bits(a[3]);
        o[4] = (short)f32_to_bf16bits(b[0]); o[5] = (short)f32_to_bf16bits(b[1]);
        o[6] = (short)f32_to_bf16bits(b[2]); o[7] = (short)f32_to_bf16bits(b[3]);
        *(short8*)&tile[rr * 72 + g * 8] = o;
    }
    __syncthreads();
    #pragma unroll
    for (int p = 0; p < 2; ++p) {
        int rr = r + p * 32;
        short8 v;
        #pragma unroll
        for (int i = 0; i < 8; ++i)
            v[i] = (short)tile[(g * 8 + i) * 72 + rr];
        *(short8*)(out + (size_t)(n0 + rr) * D_ + k0 + g * 8) = v;
    }
}

// ---------------------------------------------------------------------------
// fused QKV projection: 64x128 tile (occupancy over tile size -- the shape
// K=1024 is latency-bound, not staging-bound), BK=64, glds16 + XOR swizzle.
// k/v tiles whose s-range is entirely >= length[b] are skipped (masked keys
// are never read by attention).
// ---------------------------------------------------------------------------
__global__ __launch_bounds__(256) void proj_gemm(
    const ushort* __restrict__ X,    // [4096][1024] bf16
    const ushort* __restrict__ Wt,   // [3][1024][1024] bf16, n-major
    const float* __restrict__ b0, const float* __restrict__ b1,
    const float* __restrict__ b2,
    const int* __restrict__ length,
    ushort* __restrict__ qkv)        // [3][4M] bf16
{
    const int z = blockIdx.z;
    const int m0 = blockIdx.x * 64, n0 = blockIdx.y * 128;

    if (z >= 1) {   // k/v: skip tiles fully beyond this batch's length
        const int bidx = m0 >> 11;
        const int s0 = m0 & (S_ - 1);
        if (s0 >= length[bidx]) return;
    }

    const ushort* Wtz  = Wt + (size_t)z * D_ * D_;
    const float* bias = (z == 0) ? b0 : ((z == 1) ? b1 : b2);
    ushort* out = qkv + (size_t)z * M_ * D_;

    __shared__ ushort As[64 * 64];    //  8 KB, swizzled
    __shared__ ushort Bs[128 * 64];   // 16 KB, swizzled

    const int t = threadIdx.x;
    const int lane = t & 63, wid = t >> 6;
    const int quad = lane >> 4, l16 = lane & 15;
    const int wr = wid >> 1, wc = wid & 1;

    float4v acc[2][4] = {};

    for (int k0 = 0; k0 < D_; k0 += 64) {
        __syncthreads();
        #pragma unroll
        for (int j = 0; j < 2; ++j) {          // A: 512 chunks, 128/wave
            const int cid = wid * 128 + j * 64 + lane;
            const int row = cid >> 3;
            const int cl  = (cid & 7) ^ (row & 7);
            glds16(X + (size_t)(m0 + row) * D_ + k0 + cl * 8, &As[cid * 8]);
        }
        #pragma unroll
        for (int j = 0; j < 4; ++j) {          // B: 1024 chunks, 256/wave
            const int cid = wid * 256 + j * 64 + lane;
            const int row = cid >> 3;
            const int cl  = (cid & 7) ^ (row & 7);
            glds16(Wtz + (size_t)(n0 + row) * D_ + k0 + cl * 8, &Bs[cid * 8]);
        }
        __syncthreads();

        #pragma unroll
        for (int ks = 0; ks < 2; ++ks) {
            short8 a[2], bb[4];
            #pragma unroll
            for (int i = 0; i < 2; ++i) {
                const int r = wr * 32 + i * 16 + l16;
                const int ph = (ks * 4 + quad) ^ (r & 7);
                a[i] = *(short8*)&As[r * 64 + ph * 8];
            }
            #pragma unroll
            for (int j = 0; j < 4; ++j) {
                const int r = wc * 64 + j * 16 + l16;
                const int ph = (ks * 4 + quad) ^ (r & 7);
                bb[j] = *(short8*)&Bs[r * 64 + ph * 8];
            }
            #pragma unroll
            for (int i = 0; i < 2; ++i)
                #pragma unroll
                for (int j = 0; j < 4; ++j)
                    acc[i][j] = __builtin_amdgcn_mfma_f32_16x16x32_bf16(
                        a[i], bb[j], acc[i][j], 0, 0, 0);
        }
    }

    // epilogue: +bias, cast bf16, scatter into head layout
    #pragma unroll
    for (int j = 0; j < 4; ++j) {
        const int col = n0 + wc * 64 + j * 16 + l16;
        const float bv = bias[col];
        const int h = col >> 6, dk = col & (DK_ - 1);
        #pragma unroll
        for (int i = 0; i < 2; ++i) {
            #pragma unroll
            for (int rr = 0; rr < 4; ++rr) {
                const int row = m0 + wr * 32 + i * 16 + quad * 4 + rr;
                const int bidx = row >> 11;
                const int s = row & (S_ - 1);
                const float v = acc[i][j][rr] + bv;
                size_t addr;
                if (z == 2)
                    addr = ((size_t)(bidx * H_ + h) * DK_ + dk) * S_ + s;
                else
                    addr = ((size_t)(bidx * H_ + h) * S_ + s) * DK_ + dk;
                out[addr] = f32_to_bf16bits(v);
            }
        }
    }
}

// ---------------------------------------------------------------------------
// attention: block = (b, h, 64 q-rows), 4 waves x 16 q-rows.  32 KB LDS ->
// 5 blocks/CU.  Raw exp (reference has no max-sub) => plain accumulation of
// exp row-sums and un-normalized P@V over 64-wide k-tiles; skip tiles beyond
// length[b]; normalize once.
// ---------------------------------------------------------------------------
__global__ __launch_bounds__(256) void attention(
    const ushort* __restrict__ qkv, const int* __restrict__ length,
    float* __restrict__ out)
{
    const int b = blockIdx.z, h = blockIdx.y, q0 = blockIdx.x * 64;
    int len = length[b];
    if (len > S_) len = S_;
    if (len < 1) len = 1;
    const int nkt = (len + 63) >> 6;

    const ushort* qb = qkv + ((size_t)(b * H_ + h) * S_ + q0) * DK_;
    const ushort* kb = qkv + (size_t)M_ * D_ + (size_t)(b * H_ + h) * S_ * DK_;
    const ushort* vb = qkv + (size_t)2 * M_ * D_ + (size_t)(b * H_ + h) * DK_ * S_;

    __shared__ ushort Qs[64 * 64];   // [q][dk]   8 KB swizzled
    __shared__ ushort Ks[64 * 64];   // [key][dk] 8 KB swizzled
    __shared__ ushort Vs[64 * 64];   // [dk][key] 8 KB swizzled
    __shared__ ushort Ps[64 * 64];   // [q][key]  8 KB swizzled, wave-private rows

    const int t = threadIdx.x, lane = t & 63, wid = t >> 6;
    const int quad = lane >> 4, l16 = lane & 15;
    const int qr = wid * 16 + l16;   // this lane's A-row (q_local)

    // stage Q once: 512 chunks, 128/wave
    #pragma unroll
    for (int j = 0; j < 2; ++j) {
        const int cid = wid * 128 + j * 64 + lane;
        const int row = cid >> 3;
        const int cl  = (cid & 7) ^ (row & 7);
        glds16(qb + (size_t)row * DK_ + cl * 8, &Qs[cid * 8]);
    }

    float4v cacc[4] = {};
    float rs[4] = {};

    for (int kt = 0; kt < nkt; ++kt) {
        __syncthreads();
        #pragma unroll
        for (int j = 0; j < 2; ++j) {
            const int cid = wid * 128 + j * 64 + lane;
            const int row = cid >> 3;
            const int cl  = (cid & 7) ^ (row & 7);
            glds16(kb + (size_t)(kt * 64 + row) * DK_ + cl * 8, &Ks[cid * 8]);
            glds16(vb + (size_t)row * S_ + kt * 64 + cl * 8,    &Vs[cid * 8]);
        }
        __syncthreads();

        // S-strip = Q K^T (16 q-rows x 64 keys)
        float4v sacc[4] = {};
        #pragma unroll
        for (int ks = 0; ks < 2; ++ks) {
            const int pha = (ks * 4 + quad) ^ (qr & 7);
            short8 a = *(short8*)&Qs[qr * 64 + pha * 8];
            #pragma unroll
            for (int ct = 0; ct < 4; ++ct) {
                const int kr = ct * 16 + l16;
                const int phb = (ks * 4 + quad) ^ (kr & 7);
                short8 bb = *(short8*)&Ks[kr * 64 + phb * 8];
                sacc[ct] = __builtin_amdgcn_mfma_f32_16x16x32_bf16(
                    a, bb, sacc[ct], 0, 0, 0);
            }
        }

        // exp + mask + rowsum; write P strip (C-layout -> swizzled LDS)
        #pragma unroll
        for (int ct = 0; ct < 4; ++ct) {
            const int key = kt * 64 + ct * 16 + l16;
            const int c   = ct * 2 + (l16 >> 3);
            #pragma unroll
            for (int rr = 0; rr < 4; ++rr) {
                const int prow = wid * 16 + quad * 4 + rr;
                float val = 0.f;
                if (key < len) val = __expf(sacc[ct][rr] * 0.125f);
                rs[rr] += val;
                const int ph = c ^ (prow & 7);
                Ps[prow * 64 + ph * 8 + (l16 & 7)] = f32_to_bf16bits(val);
            }
        }

        // P @ V  (strip is wave-private: same-wave LDS RAW, no barrier)
        #pragma unroll
        for (int ks = 0; ks < 2; ++ks) {
            const int pha = (ks * 4 + quad) ^ (qr & 7);
            short8 ap = *(short8*)&Ps[qr * 64 + pha * 8];
            #pragma unroll
            for (int ct = 0; ct < 4; ++ct) {
                const int vr = ct * 16 + l16;
                const int phb = (ks * 4 + quad) ^ (vr & 7);
                short8 vv = *(short8*)&Vs[vr * 64 + phb * 8];
                cacc[ct] = __builtin_amdgcn_mfma_f32_16x16x32_bf16(
                    ap, vv, cacc[ct], 0, 0, 0);
            }
        }
    }

    // reduce row-sums across the 16 lanes of each quad-row group
    #pragma unroll
    for (int rr = 0; rr < 4; ++rr) {
        float v = rs[rr];
        #pragma unroll
        for (int off = 1; off < 16; off <<= 1)
            v += __shfl_xor(v, off, 16);
        rs[rr] = v;
    }

    // normalize + store fp32
    #pragma unroll
    for (int ct = 0; ct < 4; ++ct)
        #pragma unroll
        for (int rr = 0; rr < 4; ++rr) {
            const int q = q0 + wid * 16 + quad * 4 + rr;
            const int d = h * 64 + ct * 16 + l16;
            out[((size_t)b * S_ + q) * D_ + d] = cacc[ct][rr] / (rs[rr] + 1e-8f);
        }
}

// ---------------------------------------------------------------------------
extern "C" void kernel_launch(void* const* d_in, const int* in_sizes, int n_in,
                              void* d_out, int out_size, void* d_ws, size_t ws_size,
                              hipStream_t stream)
{
    const float* Q   = (const float*)d_in[0];
    const int*   len = (const int*)d_in[1];
    const float* Wq  = (const float*)d_in[2];
    const float* bq  = (const float*)d_in[3];
    const float* Wk  = (const float*)d_in[4];
    const float* bk  = (const float*)d_in[5];
    const float* Wv  = (const float*)d_in[6];
    const float* bv  = (const float*)d_in[7];
    float* out = (float*)d_out;

    ushort* ws  = (ushort*)d_ws;
    ushort* Xb  = ws;                                   // 4M bf16 = 8 MB
    ushort* Wt  = ws + (size_t)M_ * D_;                 // 3M bf16 = 6 MB
    ushort* qkv = Wt + (size_t)3 * D_ * D_;             // 12M bf16 = 24 MB

    dim3 gPr(16, 16, 11);
    prep<<<gPr, 256, 0, stream>>>(Q, Wq, Wk, Wv, Xb, Wt);

    dim3 gP(M_ / 64, D_ / 128, 3);
    proj_gemm<<<gP, 256, 0, stream>>>(Xb, Wt, bq, bk, bv, len, qkv);

    dim3 gA(S_ / 64, H_, B_);
    attention<<<gA, 256, 0, stream>>>(qkv, len, out);
}

// Round 5
// 167.783 us; speedup vs baseline: 1.1538x; 1.0549x over previous
//
#include <hip/hip_runtime.h>
#include <hip/hip_bf16.h>

#define B_  2
#define S_  2048
#define D_  1024
#define H_  16
#define DK_ 64
#define M_  (B_ * S_)   // 4096

typedef short short8 __attribute__((ext_vector_type(8)));
typedef float float4v __attribute__((ext_vector_type(4)));

// log2(e)/8 : folded into Q at projection so attention exp is a bare v_exp_f32
#define QSCALE 0.18033688011112042f

static __device__ __forceinline__ ushort f32_to_bf16bits(float f) {
    union { __hip_bfloat16 h; ushort u; } cv;
    cv.h = __float2bfloat16(f);
    return cv.u;
}
static __device__ __forceinline__ unsigned pk2(float a, float b) {
    return (unsigned)f32_to_bf16bits(a) | ((unsigned)f32_to_bf16bits(b) << 16);
}

// async global->LDS, 16B per lane (lands at wave-uniform base + lane*16)
static __device__ __forceinline__ void glds16(const ushort* g, ushort* l) {
    __builtin_amdgcn_global_load_lds(
        (const __attribute__((address_space(1))) unsigned int*)g,
        (__attribute__((address_space(3))) unsigned int*)l, 16, 0, 0);
}

// ---------------------------------------------------------------------------
// prep: z in [0,3) -> transpose+convert W_z[k][n] fp32 -> Wt[n][k] bf16
//       z in [3,11) -> convert X fp32 -> bf16
// ---------------------------------------------------------------------------
__global__ __launch_bounds__(256) void prep(
    const float* __restrict__ X, const float* __restrict__ W0,
    const float* __restrict__ W1, const float* __restrict__ W2,
    ushort* __restrict__ Xb, ushort* __restrict__ Wt)
{
    const int z = blockIdx.z;
    const int t = threadIdx.x;

    if (z >= 3) {   // convert X
        const int blk = (z - 3) * 256 + blockIdx.y * 16 + blockIdx.x;
        const int i = blk * 2048 + t * 8;
        float4v a = *(const float4v*)(X + i);
        float4v b = *(const float4v*)(X + i + 4);
        short8 o;
        o[0] = (short)f32_to_bf16bits(a[0]); o[1] = (short)f32_to_bf16bits(a[1]);
        o[2] = (short)f32_to_bf16bits(a[2]); o[3] = (short)f32_to_bf16bits(a[3]);
        o[4] = (short)f32_to_bf16bits(b[0]); o[5] = (short)f32_to_bf16bits(b[1]);
        o[6] = (short)f32_to_bf16bits(b[2]); o[7] = (short)f32_to_bf16bits(b[3]);
        *(short8*)(Xb + i) = o;
        return;
    }

    const float* W = (z == 0) ? W0 : ((z == 1) ? W1 : W2);
    ushort* out = Wt + (size_t)z * D_ * D_;

    __shared__ ushort tile[64 * 72];
    int n0 = blockIdx.x * 64, k0 = blockIdx.y * 64;
    int r = t >> 3, g = t & 7;

    #pragma unroll
    for (int p = 0; p < 2; ++p) {
        int rr = r + p * 32;
        const float* src = W + (size_t)(k0 + rr) * D_ + n0 + g * 8;
        float4v a = *(const float4v*)src;
        float4v b = *(const float4v*)(src + 4);
        short8 o;
        o[0] = (short)f32_to_bf16bits(a[0]); o[1] = (short)f32_to_bf16bits(a[1]);
        o[2] = (short)f32_to_bf16bits(a[2]); o[3] = (short)f32_to_bf16bits(a[3]);
        o[4] = (short)f32_to_bf16bits(b[0]); o[5] = (short)f32_to_bf16bits(b[1]);
        o[6] = (short)f32_to_bf16bits(b[2]); o[7] = (short)f32_to_bf16bits(b[3]);
        *(short8*)&tile[rr * 72 + g * 8] = o;
    }
    __syncthreads();
    #pragma unroll
    for (int p = 0; p < 2; ++p) {
        int rr = r + p * 32;
        short8 v;
        #pragma unroll
        for (int i = 0; i < 8; ++i)
            v[i] = (short)tile[(g * 8 + i) * 72 + rr];
        *(short8*)(out + (size_t)(n0 + rr) * D_ + k0 + g * 8) = v;
    }
}

// ---------------------------------------------------------------------------
// fused QKV projection: 64x128 tile, BK=64, glds16 + XOR swizzle, DOUBLE-
// BUFFERED staging (issue next tile's glds before computing current; single
// barrier per iter drains loads that had a full compute phase in flight).
// z==0 (Q) epilogue folds score-scale*log2e into the values.
// k/v m-tiles fully beyond length[b] are skipped.
// ---------------------------------------------------------------------------
__global__ __launch_bounds__(256, 3) void proj_gemm(
    const ushort* __restrict__ X,    // [4096][1024] bf16
    const ushort* __restrict__ Wt,   // [3][1024][1024] bf16, n-major
    const float* __restrict__ b0, const float* __restrict__ b1,
    const float* __restrict__ b2,
    const int* __restrict__ length,
    ushort* __restrict__ qkv)        // [3][4M] bf16
{
    const int z = blockIdx.z;
    const int m0 = blockIdx.x * 64, n0 = blockIdx.y * 128;

    if (z >= 1) {   // k/v: skip tiles fully beyond this batch's length
        const int bidx = m0 >> 11;
        const int s0 = m0 & (S_ - 1);
        if (s0 >= length[bidx]) return;
    }

    const ushort* Wtz  = Wt + (size_t)z * D_ * D_;
    const float* bias = (z == 0) ? b0 : ((z == 1) ? b1 : b2);
    ushort* out = qkv + (size_t)z * M_ * D_;

    __shared__ __align__(16) ushort As[2][64 * 64];    // 2 x  8 KB
    __shared__ __align__(16) ushort Bs[2][128 * 64];   // 2 x 16 KB

    const int t = threadIdx.x;
    const int lane = t & 63, wid = t >> 6;
    const int quad = lane >> 4, l16 = lane & 15;
    const int wr = wid >> 1, wc = wid & 1;

    float4v acc[2][4] = {};

    // stage k-tile 0 into buffer 0
    #pragma unroll
    for (int j = 0; j < 2; ++j) {
        const int cid = wid * 128 + j * 64 + lane;
        const int row = cid >> 3;
        const int cl  = (cid & 7) ^ (row & 7);
        glds16(X + (size_t)(m0 + row) * D_ + cl * 8, &As[0][cid * 8]);
    }
    #pragma unroll
    for (int j = 0; j < 4; ++j) {
        const int cid = wid * 256 + j * 64 + lane;
        const int row = cid >> 3;
        const int cl  = (cid & 7) ^ (row & 7);
        glds16(Wtz + (size_t)(n0 + row) * D_ + cl * 8, &Bs[0][cid * 8]);
    }
    __syncthreads();

    for (int kt = 0; kt < 16; ++kt) {
        const int cur = kt & 1, nxt = cur ^ 1;
        if (kt + 1 < 16) {
            const int k0 = (kt + 1) * 64;
            #pragma unroll
            for (int j = 0; j < 2; ++j) {
                const int cid = wid * 128 + j * 64 + lane;
                const int row = cid >> 3;
                const int cl  = (cid & 7) ^ (row & 7);
                glds16(X + (size_t)(m0 + row) * D_ + k0 + cl * 8, &As[nxt][cid * 8]);
            }
            #pragma unroll
            for (int j = 0; j < 4; ++j) {
                const int cid = wid * 256 + j * 64 + lane;
                const int row = cid >> 3;
                const int cl  = (cid & 7) ^ (row & 7);
                glds16(Wtz + (size_t)(n0 + row) * D_ + k0 + cl * 8, &Bs[nxt][cid * 8]);
            }
        }

        #pragma unroll
        for (int ks = 0; ks < 2; ++ks) {
            short8 a[2], bb[4];
            #pragma unroll
            for (int i = 0; i < 2; ++i) {
                const int r = wr * 32 + i * 16 + l16;
                const int ph = (ks * 4 + quad) ^ (r & 7);
                a[i] = *(short8*)&As[cur][r * 64 + ph * 8];
            }
            #pragma unroll
            for (int j = 0; j < 4; ++j) {
                const int r = wc * 64 + j * 16 + l16;
                const int ph = (ks * 4 + quad) ^ (r & 7);
                bb[j] = *(short8*)&Bs[cur][r * 64 + ph * 8];
            }
            #pragma unroll
            for (int i = 0; i < 2; ++i)
                #pragma unroll
                for (int j = 0; j < 4; ++j)
                    acc[i][j] = __builtin_amdgcn_mfma_f32_16x16x32_bf16(
                        a[i], bb[j], acc[i][j], 0, 0, 0);
        }
        __syncthreads();   // drains next-stage glds (in flight during compute)
    }

    // epilogue: +bias; z==0 pre-scales by log2(e)/8; scatter into head layout
    const float sc = (z == 0) ? QSCALE : 1.0f;
    #pragma unroll
    for (int j = 0; j < 4; ++j) {
        const int col = n0 + wc * 64 + j * 16 + l16;
        const float bv = bias[col];
        const int h = col >> 6, dk = col & (DK_ - 1);
        #pragma unroll
        for (int i = 0; i < 2; ++i) {
            #pragma unroll
            for (int rr = 0; rr < 4; ++rr) {
                const int row = m0 + wr * 32 + i * 16 + quad * 4 + rr;
                const int bidx = row >> 11;
                const int s = row & (S_ - 1);
                const float v = (acc[i][j][rr] + bv) * sc;
                size_t addr;
                if (z == 2)
                    addr = ((size_t)(bidx * H_ + h) * DK_ + dk) * S_ + s;
                else
                    addr = ((size_t)(bidx * H_ + h) * S_ + s) * DK_ + dk;
                out[addr] = f32_to_bf16bits(v);
            }
        }
    }
}

// ---------------------------------------------------------------------------
// attention: block = (b, h, 64 q-rows), 4 waves x 16-q strips.
// S^T trick: compute S^T = K*Q^T so the MFMA C-layout hands each lane 4
// CONSECUTIVE keys per q -> P strip written as 4 packed ds_write_b64 (vs 16
// scalar b16).  Even-XOR 8B-chunk swizzle on Ps keeps PV's ds_read_b128
// legal and ~conflict-free.  Q pre-scaled: score exp = bare v_exp_f32.
// K/V staging double-buffered; interior tiles skip mask cmps.
// ---------------------------------------------------------------------------
__global__ __launch_bounds__(256, 3) void attention(
    const ushort* __restrict__ qkv, const int* __restrict__ length,
    float* __restrict__ out)
{
    const int b = blockIdx.z, h = blockIdx.y, q0 = blockIdx.x * 64;
    int len = length[b];
    if (len > S_) len = S_;
    if (len < 1) len = 1;
    const int nkt = (len + 63) >> 6;

    const ushort* qb = qkv + ((size_t)(b * H_ + h) * S_ + q0) * DK_;
    const ushort* kb = qkv + (size_t)M_ * D_ + (size_t)(b * H_ + h) * S_ * DK_;
    const ushort* vb = qkv + (size_t)2 * M_ * D_ + (size_t)(b * H_ + h) * DK_ * S_;

    __shared__ __align__(16) ushort Qs[64 * 64];       //  8 KB [q][dk]
    __shared__ __align__(16) ushort Ks[2][64 * 64];    // 16 KB [key][dk]
    __shared__ __align__(16) ushort Vs[2][64 * 64];    // 16 KB [dk][key]
    __shared__ __align__(16) ushort Ps[64 * 64];       //  8 KB [q][key], 8B-swizzle

    const int t = threadIdx.x, lane = t & 63, wid = t >> 6;
    const int quad = lane >> 4, l16 = lane & 15;
    const int qrow = wid * 16 + l16;
    const int e8 = (l16 & 7) << 1;   // even XOR phase for Ps (row&7 == l16&7)

    // stage Q (once) + K/V tile 0
    #pragma unroll
    for (int j = 0; j < 2; ++j) {
        const int cid = wid * 128 + j * 64 + lane;
        const int row = cid >> 3;
        const int cl  = (cid & 7) ^ (row & 7);
        glds16(qb + (size_t)row * DK_ + cl * 8, &Qs[cid * 8]);
        glds16(kb + (size_t)row * DK_ + cl * 8, &Ks[0][cid * 8]);
        glds16(vb + (size_t)row * S_ + cl * 8,  &Vs[0][cid * 8]);
    }
    __syncthreads();

    float4v cacc[4] = {};
    float rs = 0.f;

    for (int kt = 0; kt < nkt; ++kt) {
        const int cur = kt & 1, nxt = cur ^ 1;
        if (kt + 1 < nkt) {
            #pragma unroll
            for (int j = 0; j < 2; ++j) {
                const int cid = wid * 128 + j * 64 + lane;
                const int row = cid >> 3;
                const int cl  = (cid & 7) ^ (row & 7);
                glds16(kb + (size_t)((kt + 1) * 64 + row) * DK_ + cl * 8,
                       &Ks[nxt][cid * 8]);
                glds16(vb + (size_t)row * S_ + (kt + 1) * 64 + cl * 8,
                       &Vs[nxt][cid * 8]);
            }
        }

        // S^T tile: A = K-frag (m=key), B = Q-frag (n=q).  D[key][q]:
        // lane holds q = l16 (col), keys = ct*16 + quad*4 + rr (rows).
        float4v sacc[4] = {};
        #pragma unroll
        for (int ks = 0; ks < 2; ++ks) {
            const int phb = (ks * 4 + quad) ^ (l16 & 7);
            short8 bq8 = *(short8*)&Qs[qrow * 64 + phb * 8];
            #pragma unroll
            for (int ct = 0; ct < 4; ++ct) {
                const int krow = ct * 16 + l16;
                const int pha = (ks * 4 + quad) ^ (krow & 7);
                short8 ak = *(short8*)&Ks[cur][krow * 64 + pha * 8];
                sacc[ct] = __builtin_amdgcn_mfma_f32_16x16x32_bf16(
                    ak, bq8, sacc[ct], 0, 0, 0);
            }
        }

        // exp2 + (boundary-only) mask + rowsum + packed P write
        const bool full = ((kt + 1) * 64 <= len);
        #pragma unroll
        for (int ct = 0; ct < 4; ++ct) {
            float v0 = __builtin_amdgcn_exp2f(sacc[ct][0]);
            float v1 = __builtin_amdgcn_exp2f(sacc[ct][1]);
            float v2 = __builtin_amdgcn_exp2f(sacc[ct][2]);
            float v3 = __builtin_amdgcn_exp2f(sacc[ct][3]);
            if (!full) {
                const int kb0 = kt * 64 + ct * 16 + quad * 4;
                v0 = (kb0 + 0 < len) ? v0 : 0.f;
                v1 = (kb0 + 1 < len) ? v1 : 0.f;
                v2 = (kb0 + 2 < len) ? v2 : 0.f;
                v3 = (kb0 + 3 < len) ? v3 : 0.f;
            }
            rs += (v0 + v1) + (v2 + v3);
            uint2 w;
            w.x = pk2(v0, v1);
            w.y = pk2(v2, v3);
            const int c8 = (ct * 4 + quad) ^ e8;        // 8B-chunk swizzle
            *(uint2*)&Ps[qrow * 64 + c8 * 4] = w;
        }

        // P @ V: A = P-frag (m=q, k=key), B = V-frag from Vs (n=d).
        // Strip is wave-private: same-wave LDS RAW, no barrier needed.
        #pragma unroll
        for (int ks = 0; ks < 2; ++ks) {
            const int pp = ((ks * 4 + quad) * 2) ^ e8;   // first 8B chunk (even)
            short8 ap = *(short8*)&Ps[qrow * 64 + pp * 4];
            #pragma unroll
            for (int ct = 0; ct < 4; ++ct) {
                const int vrow = ct * 16 + l16;
                const int phv = (ks * 4 + quad) ^ (vrow & 7);
                short8 vv = *(short8*)&Vs[cur][vrow * 64 + phv * 8];
                cacc[ct] = __builtin_amdgcn_mfma_f32_16x16x32_bf16(
                    ap, vv, cacc[ct], 0, 0, 0);
            }
        }
        __syncthreads();   // next-stage glds drained; buf[cur] free for kt+2
    }

    // row-sum: lane holds partial for q = l16-group; reduce across quads
    rs += __shfl_xor(rs, 16);
    rs += __shfl_xor(rs, 32);

    // normalize + store fp32.  C-layout: col = d-offset = l16, row = q-offset
    // = quad*4+rr; fetch rs(q=quad*4+rr) from lane group via width-16 shuffle.
    #pragma unroll
    for (int rr = 0; rr < 4; ++rr) {
        const float rsq = __shfl(rs, quad * 4 + rr, 16);
        const float inv = 1.0f / (rsq + 1e-8f);
        const int q = q0 + wid * 16 + quad * 4 + rr;
        #pragma unroll
        for (int ct = 0; ct < 4; ++ct) {
            const int d = h * 64 + ct * 16 + l16;
            out[((size_t)b * S_ + q) * D_ + d] = cacc[ct][rr] * inv;
        }
    }
}

// ---------------------------------------------------------------------------
extern "C" void kernel_launch(void* const* d_in, const int* in_sizes, int n_in,
                              void* d_out, int out_size, void* d_ws, size_t ws_size,
                              hipStream_t stream)
{
    const float* Q   = (const float*)d_in[0];
    const int*   len = (const int*)d_in[1];
    const float* Wq  = (const float*)d_in[2];
    const float* bq  = (const float*)d_in[3];
    const float* Wk  = (const float*)d_in[4];
    const float* bk  = (const float*)d_in[5];
    const float* Wv  = (const float*)d_in[6];
    const float* bv  = (const float*)d_in[7];
    float* out = (float*)d_out;

    ushort* ws  = (ushort*)d_ws;
    ushort* Xb  = ws;                                   // 4M bf16 = 8 MB
    ushort* Wt  = ws + (size_t)M_ * D_;                 // 3M bf16 = 6 MB
    ushort* qkv = Wt + (size_t)3 * D_ * D_;             // 12M bf16 = 24 MB

    dim3 gPr(16, 16, 11);
    prep<<<gPr, 256, 0, stream>>>(Q, Wq, Wk, Wv, Xb, Wt);

    dim3 gP(M_ / 64, D_ / 128, 3);
    proj_gemm<<<gP, 256, 0, stream>>>(Xb, Wt, bq, bk, bv, len, qkv);

    dim3 gA(S_ / 64, H_, B_);
    attention<<<gA, 256, 0, stream>>>(qkv, len, out);
}